// Round 6
// baseline (79.201 us; speedup 1.0000x reference)
//
#include <hip/hip_runtime.h>
#include <hip/hip_bf16.h>

// 4-qubit QNN: encoding RY(x) per sample + fixed variational block (shared
// weights) + <Z_q> readout.  The variational block is a constant 16x16
// unitary U; <Z_q> = s0^T Re(U^+ Z_q U) s0 with s0 a product state in
// v(t)=[cos(t/2),sin(t/2)].  Each output collapses to a 5x5 bilinear form
// in the degree-4 monomials of (c0,s0) and (c1,s1):
//   out_q = sum_{m,n} C[q][m][n] * c0^{4-m} s0^m * c1^{4-n} s1^n
//
// v7: R1-R5 post-mortem identified the REAL bottleneck: the U-build
// prologue/setup was ONE wave running a ~2000-5600-instruction serial
// dependency chain (36 serial ocml sincos + butterflies) = 10-25us of
// single-wave latency; in fused form 4 replicas/CU convoyed to the
// directly-measured 50-56us (R2: VALUBusy 13%, occupancy 19%).  Batch-side
// edits (coeff location, trig flavor, tiling) never moved totals because
// the streaming loop was already ~5us.  Fix: single fused launch with a
// PARALLEL prologue -- 36 lanes compute all gate sin/cos concurrently into
// LDS (one trig latency, not 36 serial), and the 16-column evolution chain
// shrinks to ~250 dependent FMAs (~0.5us).  Streaming phase = proven v6.

__device__ __forceinline__ float2 mul2(float2 a, float2 b) {
    return make_float2(a.x * b.x, a.y * b.y);
}
__device__ __forceinline__ float2 fma2(float s, float2 a, float2 b) {
    return make_float2(fmaf(s, a.x, b.x), fmaf(s, a.y, b.y));
}

__global__ __launch_bounds__(256) void qnn_fused(const float2* __restrict__ x2,
                                                 const float* __restrict__ w,
                                                 float4* __restrict__ out,
                                                 int B) {
    __shared__ float Ur[16][16];
    __shared__ float Ui[16][16];
    __shared__ float gs[36];                    // per-gate sin(theta/2)
    __shared__ float gc[36];                    // per-gate cos(theta/2)
    __shared__ __align__(16) float Csh[100];    // [mn][q], mn = m*5+n
    const int t = threadIdx.x;

    // ---- parallel trig: one lane per gate angle (was: 36 serial ocml) ----
    if (t < 100) Csh[t] = 0.0f;
    if (t < 36) {
        const float th = w[t] * 0.5f;           // w is [l][wq][p] flattened
        gs[t] = __sinf(th);
        gc[t] = __cosf(th);
    }
    __syncthreads();

    // ---- column evolution: thread t owns column t of U ----
    if (t < 16) {
        float ar[16], ai[16];
#pragma unroll
        for (int i = 0; i < 16; i++) { ar[i] = (i == t) ? 1.0f : 0.0f; ai[i] = 0.0f; }

#pragma unroll
        for (int l = 0; l < 3; l++) {
#pragma unroll
            for (int wq = 0; wq < 4; wq++) {
                const int st = 1 << (3 - wq);   // wire wq lives at bit (3-wq)
                const int g0 = (l * 4 + wq) * 3;
                // wave-uniform LDS broadcasts; compiler may hoist/pipeline
                const float sx = gs[g0 + 0], cx = gc[g0 + 0];
                const float sy = gs[g0 + 1], cy = gc[g0 + 1];
                const float sz = gs[g0 + 2], cz = gc[g0 + 2];
                // RX:  a' = c*a - i s*b ; b' = -i s*a + c*b
#pragma unroll
                for (int lo = 0; lo < 16; lo++) if (!(lo & st)) {
                    const int hi = lo | st;
                    const float arl = ar[lo], ail = ai[lo], arh = ar[hi], aih = ai[hi];
                    ar[lo] = cx * arl + sx * aih;
                    ai[lo] = cx * ail - sx * arh;
                    ar[hi] = cx * arh + sx * ail;
                    ai[hi] = cx * aih - sx * arl;
                }
                // RY:  a' = c*a - s*b ; b' = s*a + c*b (real)
#pragma unroll
                for (int lo = 0; lo < 16; lo++) if (!(lo & st)) {
                    const int hi = lo | st;
                    const float arl = ar[lo], ail = ai[lo], arh = ar[hi], aih = ai[hi];
                    ar[lo] = cy * arl - sy * arh;
                    ai[lo] = cy * ail - sy * aih;
                    ar[hi] = sy * arl + cy * arh;
                    ai[hi] = sy * ail + cy * aih;
                }
                // RZ:  a' = (c - i s)*a ; b' = (c + i s)*b
#pragma unroll
                for (int lo = 0; lo < 16; lo++) if (!(lo & st)) {
                    const int hi = lo | st;
                    const float arl = ar[lo], ail = ai[lo], arh = ar[hi], aih = ai[hi];
                    ar[lo] = cz * arl + sz * ail;
                    ai[lo] = cz * ail - sz * arl;
                    ar[hi] = cz * arh - sz * aih;
                    ai[hi] = cz * aih + sz * arh;
                }
            }
            // CNOT(i, (i+1)%4), i = 0..3, applied sequentially
#pragma unroll
            for (int ci = 0; ci < 4; ci++) {
                const int cst = 1 << (3 - ci);
                const int tst = 1 << (3 - ((ci + 1) & 3));
#pragma unroll
                for (int k = 0; k < 16; k++) if ((k & cst) && !(k & tst)) {
                    const int k2 = k | tst;
                    const float tr = ar[k], ti = ai[k];
                    ar[k] = ar[k2]; ai[k] = ai[k2];
                    ar[k2] = tr;    ai[k2] = ti;
                }
            }
        }
#pragma unroll
        for (int i = 0; i < 16; i++) { Ur[i][t] = ar[i]; Ui[i][t] = ai[i]; }
    }
    __syncthreads();

    // ---- M-reduction: thread t = i*16+j computes
    // M_q[i][j] = Re(sum_k conj(U[k][i]) z_q(k) U[k][j]) and folds it into
    // Csh[(mm*5+nn)*4 + q]; mm = popcount of x0-wire bits of (i,j), nn = of
    // x1-wire bits.  Wires 0,2 (bits 3,1) carry x0; wires 1,3 carry x1.
    {
        const int i = t >> 4;
        const int j = t & 15;
        float m0 = 0.f, m1 = 0.f, m2 = 0.f, m3 = 0.f;
#pragma unroll
        for (int k = 0; k < 16; k++) {
            const float r = Ur[k][i] * Ur[k][j] + Ui[k][i] * Ui[k][j];
            m0 += ((k >> 3) & 1) ? -r : r;
            m1 += ((k >> 2) & 1) ? -r : r;
            m2 += ((k >> 1) & 1) ? -r : r;
            m3 += ((k >> 0) & 1) ? -r : r;
        }
        const int mm = ((i >> 3) & 1) + ((i >> 1) & 1) + ((j >> 3) & 1) + ((j >> 1) & 1);
        const int nn = ((i >> 2) & 1) + (i & 1) + ((j >> 2) & 1) + (j & 1);
        const int mn4 = (mm * 5 + nn) * 4;
        atomicAdd(&Csh[mn4 + 0], m0);
        atomicAdd(&Csh[mn4 + 1], m1);
        atomicAdd(&Csh[mn4 + 2], m2);
        atomicAdd(&Csh[mn4 + 3], m3);
    }
    __syncthreads();

    // ---- pin coefficients in VGPRs (25 wave-uniform ds_read_b128) ----
    const float4* __restrict__ Csh4 = (const float4*)Csh;
    float4 cv[25];
#pragma unroll
    for (int i = 0; i < 25; i++) cv[i] = Csh4[i];

    // ---- streaming phase (proven v6 structure): 1024 samples/block ----
    const int bs = blockIdx.x * 1024;

    if (bs + 1024 <= B) {
        // Fast path: hoist all 4 x-loads, then pure-register compute.
        const int sA0 = bs + t;
        const float2 xA0 = x2[sA0];
        const float2 xB0 = x2[sA0 + 256];
        const float2 xA1 = x2[sA0 + 512];
        const float2 xB1 = x2[sA0 + 768];

#pragma unroll
        for (int k = 0; k < 2; k++) {
            const float2 xA = k ? xA1 : xA0;
            const float2 xB = k ? xB1 : xB0;
            const float2 s0 = make_float2(__sinf(xA.x * 0.5f), __sinf(xB.x * 0.5f));
            const float2 c0 = make_float2(__cosf(xA.x * 0.5f), __cosf(xB.x * 0.5f));
            const float2 s1 = make_float2(__sinf(xA.y * 0.5f), __sinf(xB.y * 0.5f));
            const float2 c1 = make_float2(__cosf(xA.y * 0.5f), __cosf(xB.y * 0.5f));

            const float2 cc0 = mul2(c0, c0), ss0 = mul2(s0, s0), cs0 = mul2(c0, s0);
            const float2 cc1 = mul2(c1, c1), ss1 = mul2(s1, s1), cs1 = mul2(c1, s1);
            const float2 p0[5] = { mul2(cc0, cc0), mul2(cc0, cs0), mul2(cs0, cs0),
                                   mul2(cs0, ss0), mul2(ss0, ss0) };
            const float2 p1[5] = { mul2(cc1, cc1), mul2(cc1, cs1), mul2(cs1, cs1),
                                   mul2(cs1, ss1), mul2(ss1, ss1) };

            float2 a0 = make_float2(0.f, 0.f), a1 = a0, a2 = a0, a3 = a0;
#pragma unroll
            for (int m = 0; m < 5; m++)
#pragma unroll
                for (int n = 0; n < 5; n++) {
                    const float4 cvv = cv[m * 5 + n];      // register, static idx
                    const float2 pp = mul2(p0[m], p1[n]);
                    a0 = fma2(cvv.x, pp, a0);
                    a1 = fma2(cvv.y, pp, a1);
                    a2 = fma2(cvv.z, pp, a2);
                    a3 = fma2(cvv.w, pp, a3);
                }
            const int sA = bs + k * 512 + t;
            out[sA]       = make_float4(a0.x, a1.x, a2.x, a3.x);
            out[sA + 256] = make_float4(a0.y, a1.y, a2.y, a3.y);
        }
    } else {
        // Tail block: per-sample scalar path with bounds checks.
#pragma unroll
        for (int k = 0; k < 4; k++) {
            const int s = bs + k * 256 + t;
            if (s < B) {
                const float2 xv = x2[s];
                const float st0 = __sinf(xv.x * 0.5f), ct0 = __cosf(xv.x * 0.5f);
                const float st1 = __sinf(xv.y * 0.5f), ct1 = __cosf(xv.y * 0.5f);
                const float cc0 = ct0 * ct0, ss0 = st0 * st0, cs0 = ct0 * st0;
                const float cc1 = ct1 * ct1, ss1 = st1 * st1, cs1 = ct1 * st1;
                const float q0[5] = { cc0 * cc0, cc0 * cs0, cs0 * cs0, cs0 * ss0, ss0 * ss0 };
                const float q1[5] = { cc1 * cc1, cc1 * cs1, cs1 * cs1, cs1 * ss1, ss1 * ss1 };
                float o0 = 0.f, o1 = 0.f, o2 = 0.f, o3 = 0.f;
#pragma unroll
                for (int m = 0; m < 5; m++)
#pragma unroll
                    for (int n = 0; n < 5; n++) {
                        const float4 cvv = cv[m * 5 + n];
                        const float pp = q0[m] * q1[n];
                        o0 = fmaf(cvv.x, pp, o0);
                        o1 = fmaf(cvv.y, pp, o1);
                        o2 = fmaf(cvv.z, pp, o2);
                        o3 = fmaf(cvv.w, pp, o3);
                    }
                out[s] = make_float4(o0, o1, o2, o3);
            }
        }
    }
}

extern "C" void kernel_launch(void* const* d_in, const int* in_sizes, int n_in,
                              void* d_out, int out_size, void* d_ws, size_t ws_size,
                              hipStream_t stream) {
    const float* x = (const float*)d_in[0];      // (B, 2) float32
    const float* w = (const float*)d_in[1];      // (3, 4, 3) float32
    const int B = in_sizes[0] / 2;

    int grid = (B + 1023) / 1024;
    if (grid < 1) grid = 1;
    qnn_fused<<<grid, 256, 0, stream>>>((const float2*)x, w, (float4*)d_out, B);
}

// Round 7
// 75.143 us; speedup vs baseline: 1.0540x; 1.0540x over previous
//
#include <hip/hip_runtime.h>
#include <hip/hip_bf16.h>

// 4-qubit QNN: encoding RY(x) per sample + fixed variational block (shared
// weights) + <Z_q> readout.  The variational block is a constant 16x16
// unitary U; <Z_q> = s0^T Re(U^+ Z_q U) s0 with s0 a product state in
// v(t)=[cos(t/2),sin(t/2)].  Each output collapses to a 5x5 bilinear form
// in the degree-4 monomials of (c0,s0) and (c1,s1):
//   out_q = sum_{m,n} C[q][m][n] * c0^{4-m} s0^m * c1^{4-n} s1^n
//
// v8: R6 showed parallel trig alone recovered only ~5us: the remaining
// cost is the COLUMN-EVOLUTION chain (~7000 serial instr on wave0 of each
// block; wave0 of all co-resident blocks maps to SIMD0 -> ~24us convoy,
// matching R2's occupancy 19% / VALUBusy 13%).  Fix: 256-LANE evolution --
// each lane owns one element U[row][col]; every butterfly partner is
// lane^st (st<=8, within-wave) via __shfl_xor.  All rotations have a
// symmetric lane-local form (verified against the proven per-column code):
//   RX: ar' = c*ar + s*ai_p          ; ai' = c*ai - s*ar_p
//   RY: sgn=(row&st)?+s:-s; ar' = c*ar + sgn*ar_p; ai' = c*ai + sgn*ai_p
//   RZ: szl=(row&st)?-s:+s; ar' = c*ar + szl*ai  ; ai' = c*ai - szl*ar
//   CNOT: (row&cst) ? partner(row^tst) : keep     (cndmask)
// Chain ~72 shuffles + ~500 VALU over ALL 4 waves (~0.7us, no convoy).
// M-reduction / cv[25] pinning / streaming phase unchanged (proven v6).

__device__ __forceinline__ float2 mul2(float2 a, float2 b) {
    return make_float2(a.x * b.x, a.y * b.y);
}
__device__ __forceinline__ float2 fma2(float s, float2 a, float2 b) {
    return make_float2(fmaf(s, a.x, b.x), fmaf(s, a.y, b.y));
}

__global__ __launch_bounds__(256) void qnn_fused(const float2* __restrict__ x2,
                                                 const float* __restrict__ w,
                                                 float4* __restrict__ out,
                                                 int B) {
    __shared__ float Ur[16][16];                // [element(row)][column]
    __shared__ float Ui[16][16];
    __shared__ float gs[36];                    // per-gate sin(theta/2)
    __shared__ float gc[36];                    // per-gate cos(theta/2)
    __shared__ __align__(16) float Csh[100];    // [mn][q], mn = m*5+n
    const int t = threadIdx.x;

    // ---- parallel trig: one lane per gate angle ----
    if (t < 100) Csh[t] = 0.0f;
    if (t < 36) {
        const float th = w[t] * 0.5f;           // w is [l][wq][p] flattened
        gs[t] = __sinf(th);
        gc[t] = __cosf(th);
    }
    __syncthreads();

    // ---- 256-lane evolution: lane owns U[row][col] ----
    {
        const int row = t & 15;
        const int col = t >> 4;
        float ar = (row == col) ? 1.0f : 0.0f;
        float ai = 0.0f;

#pragma unroll
        for (int l = 0; l < 3; l++) {
#pragma unroll
            for (int wq = 0; wq < 4; wq++) {
                const int st = 1 << (3 - wq);   // wire wq lives at bit (3-wq)
                const int g0 = (l * 4 + wq) * 3;
                const float sx = gs[g0 + 0], cx = gc[g0 + 0];
                const float sy = gs[g0 + 1], cy = gc[g0 + 1];
                const float sz = gs[g0 + 2], cz = gc[g0 + 2];
                // RX (sign-symmetric in lo/hi)
                {
                    const float arp = __shfl_xor(ar, st);
                    const float aip = __shfl_xor(ai, st);
                    const float nar = cx * ar + sx * aip;
                    const float nai = cx * ai - sx * arp;
                    ar = nar; ai = nai;
                }
                // RY
                {
                    const float arp = __shfl_xor(ar, st);
                    const float aip = __shfl_xor(ai, st);
                    const float sgn = (row & st) ? sy : -sy;
                    ar = cy * ar + sgn * arp;
                    ai = cy * ai + sgn * aip;
                }
                // RZ (diagonal, no shuffle)
                {
                    const float szl = (row & st) ? -sz : sz;
                    const float nar = cz * ar + szl * ai;
                    const float nai = cz * ai - szl * ar;
                    ar = nar; ai = nai;
                }
            }
            // CNOT(ci, (ci+1)%4), ci = 0..3
#pragma unroll
            for (int ci = 0; ci < 4; ci++) {
                const int cst = 1 << (3 - ci);
                const int tst = 1 << (3 - ((ci + 1) & 3));
                const float arp = __shfl_xor(ar, tst);
                const float aip = __shfl_xor(ai, tst);
                const bool sw = (row & cst) != 0;
                ar = sw ? arp : ar;
                ai = sw ? aip : ai;
            }
        }
        Ur[row][col] = ar;
        Ui[row][col] = ai;
    }
    __syncthreads();

    // ---- M-reduction: thread t = i*16+j computes
    // M_q[i][j] = Re(sum_k conj(U[k][i]) z_q(k) U[k][j]) and folds it into
    // Csh[(mm*5+nn)*4 + q]; mm = popcount of x0-wire bits of (i,j), nn = of
    // x1-wire bits.  Wires 0,2 (bits 3,1) carry x0; wires 1,3 carry x1.
    {
        const int i = t >> 4;
        const int j = t & 15;
        float m0 = 0.f, m1 = 0.f, m2 = 0.f, m3 = 0.f;
#pragma unroll
        for (int k = 0; k < 16; k++) {
            const float r = Ur[k][i] * Ur[k][j] + Ui[k][i] * Ui[k][j];
            m0 += ((k >> 3) & 1) ? -r : r;
            m1 += ((k >> 2) & 1) ? -r : r;
            m2 += ((k >> 1) & 1) ? -r : r;
            m3 += ((k >> 0) & 1) ? -r : r;
        }
        const int mm = ((i >> 3) & 1) + ((i >> 1) & 1) + ((j >> 3) & 1) + ((j >> 1) & 1);
        const int nn = ((i >> 2) & 1) + (i & 1) + ((j >> 2) & 1) + (j & 1);
        const int mn4 = (mm * 5 + nn) * 4;
        atomicAdd(&Csh[mn4 + 0], m0);
        atomicAdd(&Csh[mn4 + 1], m1);
        atomicAdd(&Csh[mn4 + 2], m2);
        atomicAdd(&Csh[mn4 + 3], m3);
    }
    __syncthreads();

    // ---- pin coefficients in VGPRs (25 wave-uniform ds_read_b128) ----
    const float4* __restrict__ Csh4 = (const float4*)Csh;
    float4 cv[25];
#pragma unroll
    for (int i = 0; i < 25; i++) cv[i] = Csh4[i];

    // ---- streaming phase (proven v6 structure): 1024 samples/block ----
    const int bs = blockIdx.x * 1024;

    if (bs + 1024 <= B) {
        // Fast path: hoist all 4 x-loads, then pure-register compute.
        const int sA0 = bs + t;
        const float2 xA0 = x2[sA0];
        const float2 xB0 = x2[sA0 + 256];
        const float2 xA1 = x2[sA0 + 512];
        const float2 xB1 = x2[sA0 + 768];

#pragma unroll
        for (int k = 0; k < 2; k++) {
            const float2 xA = k ? xA1 : xA0;
            const float2 xB = k ? xB1 : xB0;
            const float2 s0 = make_float2(__sinf(xA.x * 0.5f), __sinf(xB.x * 0.5f));
            const float2 c0 = make_float2(__cosf(xA.x * 0.5f), __cosf(xB.x * 0.5f));
            const float2 s1 = make_float2(__sinf(xA.y * 0.5f), __sinf(xB.y * 0.5f));
            const float2 c1 = make_float2(__cosf(xA.y * 0.5f), __cosf(xB.y * 0.5f));

            const float2 cc0 = mul2(c0, c0), ss0 = mul2(s0, s0), cs0 = mul2(c0, s0);
            const float2 cc1 = mul2(c1, c1), ss1 = mul2(s1, s1), cs1 = mul2(c1, s1);
            const float2 p0[5] = { mul2(cc0, cc0), mul2(cc0, cs0), mul2(cs0, cs0),
                                   mul2(cs0, ss0), mul2(ss0, ss0) };
            const float2 p1[5] = { mul2(cc1, cc1), mul2(cc1, cs1), mul2(cs1, cs1),
                                   mul2(cs1, ss1), mul2(ss1, ss1) };

            float2 a0 = make_float2(0.f, 0.f), a1 = a0, a2 = a0, a3 = a0;
#pragma unroll
            for (int m = 0; m < 5; m++)
#pragma unroll
                for (int n = 0; n < 5; n++) {
                    const float4 cvv = cv[m * 5 + n];      // register, static idx
                    const float2 pp = mul2(p0[m], p1[n]);
                    a0 = fma2(cvv.x, pp, a0);
                    a1 = fma2(cvv.y, pp, a1);
                    a2 = fma2(cvv.z, pp, a2);
                    a3 = fma2(cvv.w, pp, a3);
                }
            const int sA = bs + k * 512 + t;
            out[sA]       = make_float4(a0.x, a1.x, a2.x, a3.x);
            out[sA + 256] = make_float4(a0.y, a1.y, a2.y, a3.y);
        }
    } else {
        // Tail block: per-sample scalar path with bounds checks.
#pragma unroll
        for (int k = 0; k < 4; k++) {
            const int s = bs + k * 256 + t;
            if (s < B) {
                const float2 xv = x2[s];
                const float st0 = __sinf(xv.x * 0.5f), ct0 = __cosf(xv.x * 0.5f);
                const float st1 = __sinf(xv.y * 0.5f), ct1 = __cosf(xv.y * 0.5f);
                const float cc0 = ct0 * ct0, ss0 = st0 * st0, cs0 = ct0 * st0;
                const float cc1 = ct1 * ct1, ss1 = st1 * st1, cs1 = ct1 * st1;
                const float q0[5] = { cc0 * cc0, cc0 * cs0, cs0 * cs0, cs0 * ss0, ss0 * ss0 };
                const float q1[5] = { cc1 * cc1, cc1 * cs1, cs1 * cs1, cs1 * ss1, ss1 * ss1 };
                float o0 = 0.f, o1 = 0.f, o2 = 0.f, o3 = 0.f;
#pragma unroll
                for (int m = 0; m < 5; m++)
#pragma unroll
                    for (int n = 0; n < 5; n++) {
                        const float4 cvv = cv[m * 5 + n];
                        const float pp = q0[m] * q1[n];
                        o0 = fmaf(cvv.x, pp, o0);
                        o1 = fmaf(cvv.y, pp, o1);
                        o2 = fmaf(cvv.z, pp, o2);
                        o3 = fmaf(cvv.w, pp, o3);
                    }
                out[s] = make_float4(o0, o1, o2, o3);
            }
        }
    }
}

extern "C" void kernel_launch(void* const* d_in, const int* in_sizes, int n_in,
                              void* d_out, int out_size, void* d_ws, size_t ws_size,
                              hipStream_t stream) {
    const float* x = (const float*)d_in[0];      // (B, 2) float32
    const float* w = (const float*)d_in[1];      // (3, 4, 3) float32
    const int B = in_sizes[0] / 2;

    int grid = (B + 1023) / 1024;
    if (grid < 1) grid = 1;
    qnn_fused<<<grid, 256, 0, stream>>>((const float2*)x, w, (float4*)d_out, B);
}